// Round 3
// baseline (214.837 us; speedup 1.0000x reference)
//
#include <hip/hip_runtime.h>
#include <hip/hip_bf16.h>

// PointConv: N=32768 points, E=786432 edges (sorted by out_index), K<=64
// product[n][c][m] = inv_n * sum_edges x_in[src][c] * celu(celu(pos_local@W1)@W2)[m]
// out[n][k] = product[n].flat(1024) @ W3[1024][64] + b3[k]

typedef __attribute__((ext_vector_type(8))) short short8;
typedef __attribute__((ext_vector_type(4))) float f32x4;

static __device__ __forceinline__ unsigned short f2bf(float f){
    unsigned int u = __float_as_uint(f);
    u += 0x7fff + ((u >> 16) & 1);     // round-to-nearest-even
    return (unsigned short)(u >> 16);
}
static __device__ __forceinline__ float rdlane(float v, int l){
    return __int_as_float(__builtin_amdgcn_readlane(__float_as_int(v), l));
}
static __device__ __forceinline__ int rfl(int v){
    return __builtin_amdgcn_readfirstlane(v);
}

// ---------------- Kernel 0: segment boundaries from sorted out_index ---------
__global__ void seg_kernel(const int* __restrict__ out_index,
                           int* __restrict__ seg_start, int E, int N)
{
    int e = blockIdx.x * blockDim.x + threadIdx.x;
    if (e >= E) return;
    int cur = out_index[e];
    if (e == 0) {
        for (int v = 0; v <= cur; ++v) seg_start[v] = 0;
    } else {
        int prev = out_index[e - 1];
        for (int v = prev + 1; v <= cur; ++v) seg_start[v] = e;
    }
    if (e == E - 1) {
        for (int v = cur + 1; v <= N; ++v) seg_start[v] = E;
    }
}

// ---------------- Kernel S: W3 -> bf16 in MFMA B-fragment layout -------------
// W3frag[((kk*4 + ntile)*64 + lane)*8 + j] = W3[kk*32 + (lane>>4)*8 + j][ntile*16 + (lane&15)]
__global__ void prep_w3(const float* __restrict__ W3,
                        unsigned short* __restrict__ W3frag)
{
    int o = blockIdx.x * blockDim.x + threadIdx.x;   // 65536 elements
    int j    = o & 7;
    int lane = (o >> 3) & 63;
    int t    = (o >> 9) & 3;
    int kk   = o >> 11;
    int k = kk * 32 + (lane >> 4) * 8 + j;
    int n = t * 16 + (lane & 15);
    W3frag[o] = f2bf(W3[k * 64 + n]);
}

// ---------------- Fused kernel: edge aggregation + W3 GEMM -------------------
// Block = 16 points. 4 waves x 4 points each (fp32 VALU edge loop, one wave per
// point at a time; lane = m, acc[c]); P staged in LDS (bf16, XOR-swizzled);
// then each wave does one 16x16 out-tile of P[16x1024] @ W3 via MFMA.
__global__ __launch_bounds__(256) void fused_kernel(
    const float* __restrict__ x_in, const float* __restrict__ pos_in,
    const float* __restrict__ pos_out, const int* __restrict__ in_index,
    const int* __restrict__ seg_start, const float* __restrict__ W1,
    const float* __restrict__ W2, const unsigned short* __restrict__ W3frag,
    const float* __restrict__ b3, float* __restrict__ out)
{
    __shared__ unsigned short P[16 * 1024];   // 32768 B exactly -> 5 blocks/CU
    int lane = threadIdx.x & 63;
    int wv = threadIdx.x >> 6;
    int blk = blockIdx.x;
    int c = lane & 15;

    // W1 column for h1[c] (dup across quads); W2 column m = lane
    float w1_0 = W1[c], w1_1 = W1[16 + c], w1_2 = W1[32 + c];
    float w2r[16];
    #pragma unroll
    for (int j = 0; j < 16; ++j) w2r[j] = W2[j * 64 + lane];

    for (int i = 0; i < 4; ++i) {
        int pt = wv * 4 + i;                       // 0..15 within block
        int n = rfl(blk * 16 + pt);
        int e0 = rfl(seg_start[n]);
        int e1v = rfl(seg_start[n + 1]);
        int cnt = e1v - e0;
        float inv = cnt > 0 ? 1.0f / (float)cnt : 0.0f;
        int e1 = e0 + (cnt > 64 ? 64 : cnt);       // dense K=64 pad clamp

        float po0 = pos_out[n * 3 + 0];
        float po1 = pos_out[n * 3 + 1];
        float po2 = pos_out[n * 3 + 2];

        float acc[16];
        #pragma unroll
        for (int j = 0; j < 16; ++j) acc[j] = 0.0f;

        if (e0 < e1) {
            // ---- software-pipelined edge loop, 2 edges/iter (A/B reg sets) ----
            int sA = rfl(in_index[e0]);
            float aP0 = pos_in[sA * 3 + 0], aP1 = pos_in[sA * 3 + 1], aP2 = pos_in[sA * 3 + 2];
            float aX[16];
            #pragma unroll
            for (int j = 0; j < 16; ++j) aX[j] = x_in[sA * 16 + j];

            for (int e = e0; e < e1; e += 2) {
                int eB = e + 1;
                int eBc = eB < e1 ? eB : e;                    // clamp (dup ok, masked)
                int sB = rfl(in_index[eBc]);
                float bP0 = pos_in[sB * 3 + 0], bP1 = pos_in[sB * 3 + 1], bP2 = pos_in[sB * 3 + 2];
                float bX[16];
                #pragma unroll
                for (int j = 0; j < 16; ++j) bX[j] = x_in[sB * 16 + j];

                int eA2 = e + 2 < e1 ? e + 2 : e;              // next A index (clamped)
                int sA2 = rfl(in_index[eA2]);

                // ---- compute edge A ----
                {
                    float p0 = aP0 - po0, p1 = aP1 - po1, p2 = aP2 - po2;
                    float h1 = fmaf(p0, w1_0, fmaf(p1, w1_1, p2 * w1_2));
                    h1 = h1 > 0.0f ? h1 : (__expf(h1) - 1.0f);
                    float s0 = 0.f, s1 = 0.f, s2 = 0.f, s3 = 0.f;
                    #pragma unroll
                    for (int j = 0; j < 16; j += 4) {
                        s0 = fmaf(rdlane(h1, j    ), w2r[j    ], s0);
                        s1 = fmaf(rdlane(h1, j + 1), w2r[j + 1], s1);
                        s2 = fmaf(rdlane(h1, j + 2), w2r[j + 2], s2);
                        s3 = fmaf(rdlane(h1, j + 3), w2r[j + 3], s3);
                    }
                    float h2 = (s0 + s1) + (s2 + s3);
                    h2 = h2 > 0.0f ? h2 : (__expf(h2) - 1.0f);
                    #pragma unroll
                    for (int j = 0; j < 16; ++j) acc[j] = fmaf(aX[j], h2, acc[j]);
                }

                // ---- rotate: issue next-A loads (cover = compute-B time) ----
                aP0 = pos_in[sA2 * 3 + 0]; aP1 = pos_in[sA2 * 3 + 1]; aP2 = pos_in[sA2 * 3 + 2];
                #pragma unroll
                for (int j = 0; j < 16; ++j) aX[j] = x_in[sA2 * 16 + j];

                // ---- compute edge B (masked if past end) ----
                {
                    float p0 = bP0 - po0, p1 = bP1 - po1, p2 = bP2 - po2;
                    float h1 = fmaf(p0, w1_0, fmaf(p1, w1_1, p2 * w1_2));
                    h1 = h1 > 0.0f ? h1 : (__expf(h1) - 1.0f);
                    float s0 = 0.f, s1 = 0.f, s2 = 0.f, s3 = 0.f;
                    #pragma unroll
                    for (int j = 0; j < 16; j += 4) {
                        s0 = fmaf(rdlane(h1, j    ), w2r[j    ], s0);
                        s1 = fmaf(rdlane(h1, j + 1), w2r[j + 1], s1);
                        s2 = fmaf(rdlane(h1, j + 2), w2r[j + 2], s2);
                        s3 = fmaf(rdlane(h1, j + 3), w2r[j + 3], s3);
                    }
                    float h2 = (s0 + s1) + (s2 + s3);
                    h2 = h2 > 0.0f ? h2 : (__expf(h2) - 1.0f);
                    h2 = (eB < e1) ? h2 : 0.0f;                // tail mask
                    #pragma unroll
                    for (int j = 0; j < 16; ++j) acc[j] = fmaf(bX[j], h2, acc[j]);
                }
            }
        }

        // write P row pt to LDS: element (c*64+m) ^ (pt*16)  [XOR swizzle]
        unsigned short* dst = P + pt * 1024;
        int sw = pt * 16;
        #pragma unroll
        for (int j = 0; j < 16; ++j) dst[(j * 64 + lane) ^ sw] = f2bf(acc[j] * inv);
    }

    __syncthreads();

    // ---- GEMM: wave wv -> out cols [wv*16, wv*16+16); A from LDS, B streamed ----
    int quad = lane >> 4, r = lane & 15;
    const unsigned short* Arow = P + r * 1024;
    int sw = r * 16;
    const short8* Bp = (const short8*)W3frag + wv * 64 + lane;

    f32x4 acc4 = {0.0f, 0.0f, 0.0f, 0.0f};
    #pragma unroll 4
    for (int kk = 0; kk < 32; ++kk) {
        short8 a = *(const short8*)(Arow + ((kk * 32 + quad * 8) ^ sw));
        short8 b = Bp[kk * 256];
        acc4 = __builtin_amdgcn_mfma_f32_16x16x32_bf16(a, b, acc4, 0, 0, 0);
    }

    int outcol = wv * 16 + r;
    float bias = b3[outcol];
    #pragma unroll
    for (int i = 0; i < 4; ++i) {
        int prow = blk * 16 + quad * 4 + i;
        out[(size_t)prow * 64 + outcol] = acc4[i] + bias;
    }
}

extern "C" void kernel_launch(void* const* d_in, const int* in_sizes, int n_in,
                              void* d_out, int out_size, void* d_ws, size_t ws_size,
                              hipStream_t stream)
{
    const float* x_in    = (const float*)d_in[0];
    const float* pos_in  = (const float*)d_in[1];
    const float* pos_out = (const float*)d_in[2];
    const int* in_index  = (const int*)d_in[3];
    const int* out_index = (const int*)d_in[4];
    const float* W1 = (const float*)d_in[5];
    const float* W2 = (const float*)d_in[6];
    const float* W3 = (const float*)d_in[7];
    const float* b3 = (const float*)d_in[8];

    int N = in_sizes[0] / 16;    // 32768
    int E = in_sizes[3];         // 786432
    float* out = (float*)d_out;

    // workspace: seg (N+1 int) | W3frag (65536 bf16)
    char* ws = (char*)d_ws;
    int* seg = (int*)ws;
    size_t offB = (((size_t)(N + 1) * 4 + 255) & ~(size_t)255);
    unsigned short* W3frag = (unsigned short*)(ws + offB);

    seg_kernel<<<(E + 255) / 256, 256, 0, stream>>>(out_index, seg, E, N);
    prep_w3<<<256, 256, 0, stream>>>(W3, W3frag);
    fused_kernel<<<N / 16, 256, 0, stream>>>(x_in, pos_in, pos_out, in_index, seg,
                                             W1, W2, W3frag, b3, out);
}

// Round 5
// 197.946 us; speedup vs baseline: 1.0853x; 1.0853x over previous
//
#include <hip/hip_runtime.h>
#include <hip/hip_bf16.h>

// PointConv: N=32768 points, E=786432 edges (sorted by out_index), K<=64
// product[n][c][m] = inv_n * sum_edges x_in[src][c] * celu(celu(pos_local@W1)@W2)[m]
// out[n][k] = product[n].flat(1024) @ W3[1024][64] + b3[k]
//
// R5: R4 with compile fixes (pkbf via manual f2bf packing; h2f16 = __fp16 vec).

typedef __attribute__((ext_vector_type(8))) short short8;
typedef __attribute__((ext_vector_type(4))) float f32x4;
typedef __fp16 h2f16 __attribute__((ext_vector_type(2)));

#if defined(__has_builtin)
#if __has_builtin(__builtin_amdgcn_fdot2)
#define HAS_FDOT2 1
#else
#define HAS_FDOT2 0
#endif
#else
#define HAS_FDOT2 0
#endif

static __device__ __forceinline__ unsigned short f2bf(float f){
    unsigned int u = __float_as_uint(f);
    u += 0x7fff + ((u >> 16) & 1);     // round-to-nearest-even
    return (unsigned short)(u >> 16);
}
static __device__ __forceinline__ unsigned int pkbf(float lo, float hi){
    return (unsigned int)f2bf(lo) | ((unsigned int)f2bf(hi) << 16);
}
static __device__ __forceinline__ int rfl(int v){
    return __builtin_amdgcn_readfirstlane(v);
}
static __device__ __forceinline__ float celu1(float x){
    return x > 0.0f ? x : (__expf(x) - 1.0f);
}

// ---------------- Kernel 0: segment boundaries from sorted out_index ---------
__global__ void seg_kernel(const int* __restrict__ out_index,
                           int* __restrict__ seg_start, int E, int N)
{
    int e = blockIdx.x * blockDim.x + threadIdx.x;
    if (e >= E) return;
    int cur = out_index[e];
    if (e == 0) {
        for (int v = 0; v <= cur; ++v) seg_start[v] = 0;
    } else {
        int prev = out_index[e - 1];
        for (int v = prev + 1; v <= cur; ++v) seg_start[v] = e;
    }
    if (e == E - 1) {
        for (int v = cur + 1; v <= N; ++v) seg_start[v] = E;
    }
}

// ---------------- Kernel P: W3 -> bf16 MFMA B-frag; W2 -> packed f16 pairs ---
// W3frag[((kk*4 + ntile)*64 + lane)*8 + j] = W3[kk*32+(lane>>4)*8+j][ntile*16+(lane&15)]
// W2pk[cp*64 + m] = half2(W2[2cp][m], W2[2cp+1][m])
__global__ void prep_kernel(const float* __restrict__ W3, const float* __restrict__ W2,
                            unsigned short* __restrict__ W3frag,
                            unsigned int* __restrict__ W2pk)
{
    int o = blockIdx.x * blockDim.x + threadIdx.x;
    if (o < 65536) {
        int j    = o & 7;
        int lane = (o >> 3) & 63;
        int t    = (o >> 9) & 3;
        int kk   = o >> 11;
        int k = kk * 32 + (lane >> 4) * 8 + j;
        int n = t * 16 + (lane & 15);
        W3frag[o] = f2bf(W3[k * 64 + n]);
    } else if (o < 65536 + 512) {
        int idx = o - 65536;
        int cp = idx >> 6, m = idx & 63;
        h2f16 pk = __builtin_amdgcn_cvt_pkrtz(W2[(2 * cp) * 64 + m],
                                              W2[(2 * cp + 1) * 64 + m]);
        W2pk[idx] = __builtin_bit_cast(unsigned int, pk);
    }
}

// ---------------- Kernel 1: edge aggregation (lane=edge, MFMA outer product) -
// Wave w owns points [8w, 8w+8). Points padded to 32-slot K-steps (1 or 2).
// Per 64-slot batch: h1 fp32 lane-parallel, h2 via fdot2 f16, celu, bf16 ->
// per-wave LDS tile H2L[e][m] (swizzled); per 32-slot step: A-frag = gathered
// x (bf16, zero for pad), B-frag from LDS, 4x mfma_f32_16x16x32_bf16 into C.
// Flush C*inv -> Pbf[n][c*64+m] on point transitions (wave-uniform).
__global__ __launch_bounds__(256) void agg_kernel(
    const float* __restrict__ x_in, const float* __restrict__ pos_in,
    const float* __restrict__ pos_out, const int* __restrict__ in_index,
    const int* __restrict__ seg_start, const float* __restrict__ W1,
    const float* __restrict__ W2, const unsigned int* __restrict__ W2pk,
    unsigned short* __restrict__ Pbf)
{
    __shared__ unsigned char ldsraw[4 * 9216];   // 64 rows x 144B per wave
    int lane = threadIdx.x & 63;
    int wv = threadIdx.x >> 6;
    unsigned char* H2L = ldsraw + wv * 9216;
    int w = blockIdx.x * 4 + wv;

    int r = lane & 15;
    int q = lane >> 4;
    int l31 = lane & 31;
    bool hihalf = lane >= 32;
    int sw = (lane >> 3) & 3;                    // row swizzle key for writes

    // per-wave point table (all wave-uniform scalars)
    int s9[9];
    #pragma unroll
    for (int i = 0; i < 9; ++i) s9[i] = rfl(seg_start[w * 8 + i]);
    int cf[8], cc[8], p[9];
    p[0] = 0;
    #pragma unroll
    for (int i = 0; i < 8; ++i) {
        cf[i] = s9[i + 1] - s9[i];               // full count (for inv)
        cc[i] = cf[i] > 64 ? 64 : cf[i];         // dense K=64 clamp
        p[i + 1] = p[i] + (cc[i] > 32 ? 2 : 1);  // 32-slot steps (>=1)
    }
    int ns = p[8];

    // W1 columns (uniform)
    float w1a[16], w1b[16], w1c[16];
    #pragma unroll
    for (int c = 0; c < 16; ++c) { w1a[c] = W1[c]; w1b[c] = W1[16 + c]; w1c[c] = W1[32 + c]; }

    f32x4 C[4];
    #pragma unroll
    for (int mt = 0; mt < 4; ++mt) C[mt] = (f32x4){0.f, 0.f, 0.f, 0.f};

    int cur_n = w * 8;
    int cur_cf = cf[0];

    for (int b = 0; b < 8; ++b) {
        if (2 * b >= ns) break;
        int tA = 2 * b, tB = 2 * b + 1;
        // select-chain: step -> point index / prefix / counts / seg base
        int iA = 0, piA = 0, iB = 0, piB = 0;
        #pragma unroll
        for (int k = 1; k < 8; ++k) {
            if (tA >= p[k]) { iA = k; piA = p[k]; }
            if (tB >= p[k]) { iB = k; piB = p[k]; }
        }
        int cfA = cf[0], ccA = cc[0], sgA = s9[0];
        int cfB = cf[0], ccB = cc[0], sgB = s9[0];
        #pragma unroll
        for (int k = 1; k < 8; ++k) {
            if (iA >= k) { cfA = cf[k]; ccA = cc[k]; sgA = s9[k]; }
            if (iB >= k) { cfB = cf[k]; ccB = cc[k]; sgB = s9[k]; }
        }
        int kbA = (tA - piA) * 32, kbB = (tB - piB) * 32;
        int nA = w * 8 + iA,       nB = w * 8 + iB;
        int remA = ccA - kbA,      remB = ccB - kbB;   // valid slots this step
        int ebA = sgA + kbA,       ebB = sgB + kbB;

        // ---- per-lane edge (lane = slot within batch) ----
        int ebH  = hihalf ? ebB : ebA;
        int remH = hihalf ? remB : remA;
        int nH   = hihalf ? nB : nA;
        int src = (l31 < remH) ? in_index[ebH + l31] : -1;
        int sc = src < 0 ? 0 : src;
        float pox = pos_out[nH * 3 + 0];
        float poy = pos_out[nH * 3 + 1];
        float poz = pos_out[nH * 3 + 2];
        float d0 = pos_in[sc * 3 + 0] - pox;
        float d1 = pos_in[sc * 3 + 1] - poy;
        float d2 = pos_in[sc * 3 + 2] - poz;

        // h1 + celu (+ f16 pack)
        float h1v[16];
        #pragma unroll
        for (int c = 0; c < 16; ++c) {
            float h = fmaf(d0, w1a[c], fmaf(d1, w1b[c], d2 * w1c[c]));
            h1v[c] = celu1(h);
        }
#if HAS_FDOT2
        h2f16 h1pk[8];
        #pragma unroll
        for (int cp = 0; cp < 8; ++cp)
            h1pk[cp] = __builtin_amdgcn_cvt_pkrtz(h1v[2 * cp], h1v[2 * cp + 1]);
#endif

        // h2 for all 64 m -> LDS row `lane` (bf16 pairs, dword-swizzled)
        unsigned char* rowp = H2L + lane * 144;
        #pragma unroll
        for (int m = 0; m < 64; m += 2) {
            float t0 = 0.f, t1 = 0.f;
#if HAS_FDOT2
            #pragma unroll
            for (int cp = 0; cp < 8; ++cp) {
                h2f16 wa = __builtin_bit_cast(h2f16, W2pk[cp * 64 + m]);
                h2f16 wb = __builtin_bit_cast(h2f16, W2pk[cp * 64 + m + 1]);
                t0 = __builtin_amdgcn_fdot2(h1pk[cp], wa, t0, false);
                t1 = __builtin_amdgcn_fdot2(h1pk[cp], wb, t1, false);
            }
#else
            #pragma unroll
            for (int c = 0; c < 16; ++c) {
                t0 = fmaf(h1v[c], W2[c * 64 + m], t0);
                t1 = fmaf(h1v[c], W2[c * 64 + m + 1], t1);
            }
#endif
            t0 = celu1(t0);
            t1 = celu1(t1);
            *(unsigned int*)(rowp + (((m >> 1) ^ (sw << 3)) << 2)) = pkbf(t0, t1);
        }

        // ---- two 32-slot K-steps: masked-x A-frag, LDS B-frags, MFMA ----
        #pragma unroll
        for (int h = 0; h < 2; ++h) {
            int nS  = h ? nB : nA;
            int cfS = h ? cfB : cfA;
            int remS = h ? remB : remA;
            int ebS  = h ? ebB : ebA;
            if (rfl(nS) != cur_n) {                      // wave-uniform transition
                float inv = cur_cf > 0 ? 1.0f / (float)cur_cf : 0.0f;
                #pragma unroll
                for (int mt = 0; mt < 4; ++mt) {
                    #pragma unroll
                    for (int i = 0; i < 4; ++i) {
                        Pbf[(size_t)cur_n * 1024 + (q * 4 + i) * 64 + mt * 16 + r] =
                            f2bf(C[mt][i] * inv);
                        C[mt][i] = 0.0f;
                    }
                }
                cur_n = nS; cur_cf = cfS;
            }
            // A-frag: x[slot 8q+j][c=r], zero for pad slots
            short8 a;
            #pragma unroll
            for (int jj = 0; jj < 4; ++jj) {
                int k0 = 8 * q + 2 * jj, k1 = k0 + 1;
                int s0 = (k0 < remS) ? in_index[ebS + k0] : -1;
                int s1 = (k1 < remS) ? in_index[ebS + k1] : -1;
                float x0 = s0 < 0 ? 0.f : x_in[s0 * 16 + r];
                float x1 = s1 < 0 ? 0.f : x_in[s1 * 16 + r];
                unsigned int pk = pkbf(x0, x1);
                a[2 * jj]     = (short)(pk & 0xffff);
                a[2 * jj + 1] = (short)(pk >> 16);
            }
            // B-frags from H2L + MFMA
            int ebL = h * 32 + 8 * q;
            #pragma unroll
            for (int mt = 0; mt < 4; ++mt) {
                int bo = ((((mt * 16 + r) >> 1) ^ (q << 3)) << 2) + (r & 1) * 2;
                short8 bb;
                #pragma unroll
                for (int j = 0; j < 8; ++j)
                    bb[j] = *(const short*)(H2L + (ebL + j) * 144 + bo);
                C[mt] = __builtin_amdgcn_mfma_f32_16x16x32_bf16(a, bb, C[mt], 0, 0, 0);
            }
        }
    }
    // final flush (last point of the wave)
    {
        float inv = cur_cf > 0 ? 1.0f / (float)cur_cf : 0.0f;
        #pragma unroll
        for (int mt = 0; mt < 4; ++mt) {
            #pragma unroll
            for (int i = 0; i < 4; ++i)
                Pbf[(size_t)cur_n * 1024 + (q * 4 + i) * 64 + mt * 16 + r] =
                    f2bf(C[mt][i] * inv);
        }
    }
}

// ---------------- Kernel 2: out = Pbf @ W3 + b3 (bf16 MFMA) ------------------
__global__ __launch_bounds__(256) void gemm_kernel(
    const unsigned short* __restrict__ Pbf,
    const unsigned short* __restrict__ W3frag,
    const float* __restrict__ b3, float* __restrict__ out)
{
    int lane = threadIdx.x & 63;
    int w = blockIdx.x * 4 + (threadIdx.x >> 6);
    int ptile = w >> 2;
    int ntile = w & 3;
    int quad = lane >> 4;
    int r = lane & 15;

    const short8* Arow = (const short8*)(Pbf + (size_t)(ptile * 16 + r) * 1024 + quad * 8);
    const short8* Bp   = (const short8*)W3frag + (size_t)ntile * 64 + lane;

    f32x4 acc = {0.0f, 0.0f, 0.0f, 0.0f};
    #pragma unroll 8
    for (int kk = 0; kk < 32; ++kk) {
        short8 a = Arow[kk * 4];          // advance 32 bf16 per step
        short8 b = Bp[(size_t)kk * 256];  // (kk*4+ntile)*64 + lane short8s
        acc = __builtin_amdgcn_mfma_f32_16x16x32_bf16(a, b, acc, 0, 0, 0);
    }

    int outcol = ntile * 16 + r;
    float bias = b3[outcol];
    #pragma unroll
    for (int i = 0; i < 4; ++i) {
        int prow = ptile * 16 + quad * 4 + i;
        out[(size_t)prow * 64 + outcol] = acc[i] + bias;
    }
}

extern "C" void kernel_launch(void* const* d_in, const int* in_sizes, int n_in,
                              void* d_out, int out_size, void* d_ws, size_t ws_size,
                              hipStream_t stream)
{
    const float* x_in    = (const float*)d_in[0];
    const float* pos_in  = (const float*)d_in[1];
    const float* pos_out = (const float*)d_in[2];
    const int* in_index  = (const int*)d_in[3];
    const int* out_index = (const int*)d_in[4];
    const float* W1 = (const float*)d_in[5];
    const float* W2 = (const float*)d_in[6];
    const float* W3 = (const float*)d_in[7];
    const float* b3 = (const float*)d_in[8];

    int N = in_sizes[0] / 16;    // 32768
    int E = in_sizes[3];         // 786432
    float* out = (float*)d_out;

    // workspace: Pbf (64MB) | seg (N+1) | W3frag (128KB) | W2pk (2KB)
    char* ws = (char*)d_ws;
    unsigned short* Pbf = (unsigned short*)ws;
    size_t off = (size_t)N * 1024 * 2;
    int* seg = (int*)(ws + off);
    off += (((size_t)(N + 1) * 4 + 255) & ~(size_t)255);
    unsigned short* W3frag = (unsigned short*)(ws + off);
    off += (size_t)65536 * 2;
    unsigned int* W2pk = (unsigned int*)(ws + off);

    seg_kernel<<<(E + 255) / 256, 256, 0, stream>>>(out_index, seg, E, N);
    prep_kernel<<<(65536 + 512 + 255) / 256, 256, 0, stream>>>(W3, W2, W3frag, W2pk);
    agg_kernel<<<N / 32, 256, 0, stream>>>(x_in, pos_in, pos_out, in_index, seg,
                                           W1, W2, W2pk, Pbf);
    gemm_kernel<<<N / 16, 256, 0, stream>>>(Pbf, W3frag, b3, out);
}

// Round 7
// 171.955 us; speedup vs baseline: 1.2494x; 1.1511x over previous
//
#include <hip/hip_runtime.h>
#include <hip/hip_bf16.h>

// PointConv: N=32768 points, E=786432 edges (sorted by out_index), K<=64
// product[n][c][m] = inv_n * sum_edges x_in[src][c] * celu(celu(pos_local@W1)@W2)[m]
// out[n][k] = product[n].flat(1024) @ W3[1024][64] + b3[k]
//
// R7: R6 + NaN fix: q>=2 A-frag lanes of the h2 MFMA read a dedicated zero
// block in LDS (uninit-LDS garbage could be Inf/NaN; garbage*0 = NaN in MFMA).

typedef __attribute__((ext_vector_type(8))) short short8;
typedef __attribute__((ext_vector_type(4))) float f32x4;
typedef __attribute__((ext_vector_type(2))) unsigned int u32x2;
typedef __attribute__((ext_vector_type(4))) unsigned int u32x4;
typedef __fp16 f16x2 __attribute__((ext_vector_type(2)));
typedef __fp16 f16x8 __attribute__((ext_vector_type(8)));

static __device__ __forceinline__ int rfl(int v){
    return __builtin_amdgcn_readfirstlane(v);
}
static __device__ __forceinline__ float celu1(float x){
    return x > 0.0f ? x : (__expf(x) - 1.0f);
}
static __device__ __forceinline__ unsigned int pkh(float lo, float hi){
    f16x2 t = __builtin_amdgcn_cvt_pkrtz(lo, hi);
    return __builtin_bit_cast(unsigned int, t);
}

// ---------------- Kernel 0: segment boundaries from sorted out_index ---------
__global__ void seg_kernel(const int* __restrict__ out_index,
                           int* __restrict__ seg_start, int E, int N)
{
    int e = blockIdx.x * blockDim.x + threadIdx.x;
    if (e >= E) return;
    int cur = out_index[e];
    if (e == 0) {
        for (int v = 0; v <= cur; ++v) seg_start[v] = 0;
    } else {
        int prev = out_index[e - 1];
        for (int v = prev + 1; v <= cur; ++v) seg_start[v] = e;
    }
    if (e == E - 1) {
        for (int v = cur + 1; v <= N; ++v) seg_start[v] = E;
    }
}

// ---------------- Kernel P: W3 -> f16 MFMA B-frag; W2 -> f16 B-frag (K-pad) --
__global__ void prep_kernel(const float* __restrict__ W3, const float* __restrict__ W2,
                            __fp16* __restrict__ W3frag,
                            unsigned int* __restrict__ W2f16)
{
    int o = blockIdx.x * blockDim.x + threadIdx.x;
    if (o < 65536) {
        int j    = o & 7;
        int lane = (o >> 3) & 63;
        int t    = (o >> 9) & 3;
        int kk   = o >> 11;
        int k = kk * 32 + (lane >> 4) * 8 + j;
        int n = t * 16 + (lane & 15);
        W3frag[o] = (__fp16)W3[k * 64 + n];
    } else if (o < 65536 + 1024) {
        int o2 = o - 65536;
        int nt   = o2 >> 8;
        int lane = (o2 >> 2) & 63;
        int d    = o2 & 3;
        int q = lane >> 4, rr = lane & 15;
        unsigned int v = 0;
        if (q < 2) {
            int k0 = q * 8 + 2 * d;
            int n = nt * 16 + rr;
            v = pkh(W2[k0 * 64 + n], W2[(k0 + 1) * 64 + n]);
        }
        W2f16[o2] = v;
    }
}

// ---------------- Kernel 1: edge aggregation (all-MFMA pipeline) -------------
// Wave w owns points [8w, 8w+8). Per 64-slot batch (2x 32-slot steps):
//   h1 (lane=edge, fp32 VALU+celu) -> LDS -> A-frags (q>=2 -> zero block) ->
//   16x MFMA h2 (f16, W2 K-padded) -> celu -> LDS H2L[m][slot] -> B-frags ->
//   8x MFMA P-accum. Flush C*inv -> Pf16[n] on wave-uniform transitions.
__global__ __launch_bounds__(256) void agg_kernel(
    const float* __restrict__ x_in, const float* __restrict__ pos_in,
    const float* __restrict__ pos_out, const int* __restrict__ in_index,
    const int* __restrict__ seg_start, const float* __restrict__ W1,
    const unsigned int* __restrict__ W2f16, __fp16* __restrict__ Pf16, int E)
{
    __shared__ __align__(16) unsigned char ldsraw[4 * 9216];
    int lane = threadIdx.x & 63;
    int wv = threadIdx.x >> 6;
    unsigned char* H2L = ldsraw + wv * 9216;   // rows: m (64) x 72 shorts (144B)
    int w = blockIdx.x * 4 + wv;

    int r = lane & 15;
    int q = lane >> 4;
    int l31 = lane & 31;
    bool hihalf = lane >= 32;

    // zero block for padded-K A-frag lanes (bytes 9200..9215: never otherwise
    // written — staging region ends at 3071, tile row 63 data ends at 9199)
    if (lane == 0) *(u32x4*)(H2L + 9200) = (u32x4){0u, 0u, 0u, 0u};

    // W2 B-frags (constant): 4 nt x 8 f16
    f16x8 bfr[4];
    #pragma unroll
    for (int nt = 0; nt < 4; ++nt)
        bfr[nt] = __builtin_bit_cast(f16x8, *((const u32x4*)W2f16 + nt * 64 + lane));

    // W1 columns (uniform -> SGPRs)
    float w1a[16], w1b[16], w1c[16];
    #pragma unroll
    for (int c = 0; c < 16; ++c) { w1a[c] = W1[c]; w1b[c] = W1[16 + c]; w1c[c] = W1[32 + c]; }

    // per-wave point table (wave-uniform)
    int s9[9];
    #pragma unroll
    for (int i = 0; i < 9; ++i) s9[i] = rfl(seg_start[w * 8 + i]);
    int cf[8], cc[8], p[9];
    p[0] = 0;
    #pragma unroll
    for (int i = 0; i < 8; ++i) {
        cf[i] = s9[i + 1] - s9[i];
        cc[i] = cf[i] > 64 ? 64 : cf[i];
        p[i + 1] = p[i] + (cc[i] > 32 ? 2 : 1);
    }
    int ns = p[8];

    f32x4 C[4];
    #pragma unroll
    for (int mt = 0; mt < 4; ++mt) C[mt] = (f32x4){0.f, 0.f, 0.f, 0.f};
    int cur_n = w * 8;
    int cur_cf = cf[0];

    #pragma unroll 1
    for (int b = 0; b < 8; ++b) {
        if (2 * b >= ns) break;
        int tA = 2 * b, tB = 2 * b + 1;
        int iA = 0, piA = 0, iB = 0, piB = 0;
        #pragma unroll
        for (int k = 1; k < 8; ++k) {
            if (tA >= p[k]) { iA = k; piA = p[k]; }
            if (tB >= p[k]) { iB = k; piB = p[k]; }
        }
        int cfA = cf[0], ccA = cc[0], sgA = s9[0];
        int cfB = cf[0], ccB = cc[0], sgB = s9[0];
        #pragma unroll
        for (int k = 1; k < 8; ++k) {
            if (iA >= k) { cfA = cf[k]; ccA = cc[k]; sgA = s9[k]; }
            if (iB >= k) { cfB = cf[k]; ccB = cc[k]; sgB = s9[k]; }
        }
        int kbA = (tA - piA) * 32, kbB = (tB - piB) * 32;
        int nA = w * 8 + iA,       nB = w * 8 + iB;
        int remA = ccA - kbA,      remB = ccB - kbB;
        int ebA = sgA + kbA,       ebB = sgB + kbB;

        // ---- x A-frags for both halves (issued early; L2-hot gathers) ----
        f16x8 ax[2];
        #pragma unroll
        for (int h = 0; h < 2; ++h) {
            int remS = h ? remB : remA;
            int ebS  = h ? ebB : ebA;
            float xv[8];
            #pragma unroll
            for (int jj = 0; jj < 8; ++jj) {
                int k = 8 * q + jj;
                int idx = ebS + k; idx = idx < E ? idx : E - 1;
                int s = in_index[idx];
                float x = x_in[s * 16 + r];
                xv[jj] = (k < remS) ? x : 0.0f;
            }
            u32x4 t;
            #pragma unroll
            for (int d = 0; d < 4; ++d) t[d] = pkh(xv[2 * d], xv[2 * d + 1]);
            ax[h] = __builtin_bit_cast(f16x8, t);
        }

        // ---- h1: lane = batch-edge (lo half = step A, hi half = step B) ----
        float poA0 = pos_out[nA * 3 + 0], poA1 = pos_out[nA * 3 + 1], poA2 = pos_out[nA * 3 + 2];
        float poB0 = pos_out[nB * 3 + 0], poB1 = pos_out[nB * 3 + 1], poB2 = pos_out[nB * 3 + 2];
        float po0 = hihalf ? poB0 : poA0;
        float po1 = hihalf ? poB1 : poA1;
        float po2 = hihalf ? poB2 : poA2;
        int ebH = hihalf ? ebB : ebA;
        int idx = ebH + l31; idx = idx < E ? idx : E - 1;
        int src = in_index[idx];
        float d0 = pos_in[src * 3 + 0] - po0;
        float d1 = pos_in[src * 3 + 1] - po1;
        float d2 = pos_in[src * 3 + 2] - po2;
        unsigned int hp[8];
        #pragma unroll
        for (int cp = 0; cp < 8; ++cp) {
            float a0 = celu1(fmaf(d0, w1a[2 * cp],     fmaf(d1, w1b[2 * cp],     d2 * w1c[2 * cp])));
            float a1 = celu1(fmaf(d0, w1a[2 * cp + 1], fmaf(d1, w1b[2 * cp + 1], d2 * w1c[2 * cp + 1])));
            hp[cp] = pkh(a0, a1);
        }
        // stage h1 row (16 f16, row stride 48B) in low H2L region
        *(u32x4*)(H2L + lane * 48)      = (u32x4){hp[0], hp[1], hp[2], hp[3]};
        *(u32x4*)(H2L + lane * 48 + 16) = (u32x4){hp[4], hp[5], hp[6], hp[7]};
        // A-frags: lane(r,q) <- h1[et*16+r][c=q*8..] for q<2; q>=2 -> zeros
        f16x8 af[4];
        #pragma unroll
        for (int et = 0; et < 4; ++et) {
            int abase = (q < 2) ? ((et * 16 + r) * 48 + q * 16) : 9200;
            af[et] = __builtin_bit_cast(f16x8, *(const u32x4*)(H2L + abase));
        }

        // ---- h2 = celu(h1 @ W2) via MFMA, 2 nt-passes; write H2L[m][slot] ----
        #pragma unroll
        for (int pp = 0; pp < 2; ++pp) {
            f32x4 D[4][2];
            #pragma unroll
            for (int et = 0; et < 4; ++et)
                #pragma unroll
                for (int j = 0; j < 2; ++j)
                    D[et][j] = __builtin_amdgcn_mfma_f32_16x16x32_f16(
                        af[et], bfr[2 * pp + j], (f32x4){0.f, 0.f, 0.f, 0.f}, 0, 0, 0);
            #pragma unroll
            for (int et = 0; et < 4; ++et)
                #pragma unroll
                for (int j = 0; j < 2; ++j) {
                    int nt = 2 * pp + j;
                    float v0 = celu1(D[et][j][0]);
                    float v1 = celu1(D[et][j][1]);
                    float v2 = celu1(D[et][j][2]);
                    float v3 = celu1(D[et][j][3]);
                    // value (edge = et*16 + q*4 + i, m = nt*16 + r)
                    *(u32x2*)(H2L + (nt * 16 + r) * 144 + et * 32 + q * 8) =
                        (u32x2){pkh(v0, v1), pkh(v2, v3)};
                }
        }

        // ---- P accumulation: per half, B-frags from H2L, 4 MFMA ----
        #pragma unroll
        for (int h = 0; h < 2; ++h) {
            int nS  = h ? nB : nA;
            int cfS = h ? cfB : cfA;
            if (rfl(nS) != cur_n) {                  // wave-uniform transition
                float inv = cur_cf > 0 ? 1.0f / (float)cur_cf : 0.0f;
                #pragma unroll
                for (int mt = 0; mt < 4; ++mt)
                    #pragma unroll
                    for (int i = 0; i < 4; ++i)
                        Pf16[(size_t)cur_n * 1024 + (q * 4 + i) * 64 + mt * 16 + r] =
                            (__fp16)(C[mt][i] * inv);
                #pragma unroll
                for (int mt = 0; mt < 4; ++mt) C[mt] = (f32x4){0.f, 0.f, 0.f, 0.f};
                cur_n = nS; cur_cf = cfS;
            }
            #pragma unroll
            for (int mt = 0; mt < 4; ++mt) {
                f16x8 bb = __builtin_bit_cast(f16x8,
                    *(u32x4*)(H2L + (mt * 16 + r) * 144 + h * 64 + q * 16));
                C[mt] = __builtin_amdgcn_mfma_f32_16x16x32_f16(ax[h], bb, C[mt], 0, 0, 0);
            }
        }
    }
    // final flush
    {
        float inv = cur_cf > 0 ? 1.0f / (float)cur_cf : 0.0f;
        #pragma unroll
        for (int mt = 0; mt < 4; ++mt)
            #pragma unroll
            for (int i = 0; i < 4; ++i)
                Pf16[(size_t)cur_n * 1024 + (q * 4 + i) * 64 + mt * 16 + r] =
                    (__fp16)(C[mt][i] * inv);
    }
}

// ---------------- Kernel 2: out = Pf16 @ W3 + b3 (f16 MFMA) ------------------
__global__ __launch_bounds__(256) void gemm_kernel(
    const __fp16* __restrict__ Pf16,
    const __fp16* __restrict__ W3frag,
    const float* __restrict__ b3, float* __restrict__ out)
{
    int lane = threadIdx.x & 63;
    int w = blockIdx.x * 4 + (threadIdx.x >> 6);
    int ptile = w >> 2;
    int ntile = w & 3;
    int quad = lane >> 4;
    int r = lane & 15;

    const short8* Arow = (const short8*)(Pf16 + (size_t)(ptile * 16 + r) * 1024 + quad * 8);
    const short8* Bp   = (const short8*)W3frag + (size_t)ntile * 64 + lane;

    f32x4 acc = {0.0f, 0.0f, 0.0f, 0.0f};
    #pragma unroll 8
    for (int kk = 0; kk < 32; ++kk) {
        f16x8 a = __builtin_bit_cast(f16x8, Arow[kk * 4]);
        f16x8 b = __builtin_bit_cast(f16x8, Bp[(size_t)kk * 256]);
        acc = __builtin_amdgcn_mfma_f32_16x16x32_f16(a, b, acc, 0, 0, 0);
    }

    int outcol = ntile * 16 + r;
    float bias = b3[outcol];
    #pragma unroll
    for (int i = 0; i < 4; ++i) {
        int prow = ptile * 16 + quad * 4 + i;
        out[(size_t)prow * 64 + outcol] = acc[i] + bias;
    }
}

extern "C" void kernel_launch(void* const* d_in, const int* in_sizes, int n_in,
                              void* d_out, int out_size, void* d_ws, size_t ws_size,
                              hipStream_t stream)
{
    const float* x_in    = (const float*)d_in[0];
    const float* pos_in  = (const float*)d_in[1];
    const float* pos_out = (const float*)d_in[2];
    const int* in_index  = (const int*)d_in[3];
    const int* out_index = (const int*)d_in[4];
    const float* W1 = (const float*)d_in[5];
    const float* W2 = (const float*)d_in[6];
    const float* W3 = (const float*)d_in[7];
    const float* b3 = (const float*)d_in[8];

    int N = in_sizes[0] / 16;    // 32768
    int E = in_sizes[3];         // 786432
    float* out = (float*)d_out;

    // workspace: Pf16 (64MB) | seg (N+1) | W3frag (128KB) | W2f16 (4KB)
    char* ws = (char*)d_ws;
    __fp16* Pf16 = (__fp16*)ws;
    size_t off = (size_t)N * 1024 * 2;
    int* seg = (int*)(ws + off);
    off += (((size_t)(N + 1) * 4 + 255) & ~(size_t)255);
    __fp16* W3frag = (__fp16*)(ws + off);
    off += (size_t)65536 * 2;
    unsigned int* W2f16 = (unsigned int*)(ws + off);

    seg_kernel<<<(E + 255) / 256, 256, 0, stream>>>(out_index, seg, E, N);
    prep_kernel<<<(65536 + 1024 + 255) / 256, 256, 0, stream>>>(W3, W2, W3frag, W2f16);
    agg_kernel<<<N / 32, 256, 0, stream>>>(x_in, pos_in, pos_out, in_index, seg,
                                           W1, W2f16, Pf16, E);
    gemm_kernel<<<N / 16, 256, 0, stream>>>(Pf16, W3frag, b3, out);
}

// Round 10
// 154.738 us; speedup vs baseline: 1.3884x; 1.1113x over previous
//
#include <hip/hip_runtime.h>
#include <hip/hip_bf16.h>

// PointConv: N=32768 points, E=786432 edges (sorted by out_index), K<=64
// product[n][c][m] = inv_n * sum_edges x_in[src][c] * celu(celu(pos_local@W1)@W2)[m]
// out[n][k] = product[n].flat(1024) @ W3[1024][64] + b3[k]
//
// R10 (= intended R8): R7 + (a) 4 points/wave (2048 blocks -> oversubscription
// smooths tail), (b) cross-batch software pipeline (prefetch next idx/pos;
// x-src via ds_bpermute of idx vector), (c) seg+prep merged into one dispatch.

typedef __attribute__((ext_vector_type(8))) short short8;
typedef __attribute__((ext_vector_type(4))) float f32x4;
typedef __attribute__((ext_vector_type(2))) unsigned int u32x2;
typedef __attribute__((ext_vector_type(4))) unsigned int u32x4;
typedef __fp16 f16x2 __attribute__((ext_vector_type(2)));
typedef __fp16 f16x8 __attribute__((ext_vector_type(8)));

static __device__ __forceinline__ int rfl(int v){
    return __builtin_amdgcn_readfirstlane(v);
}
static __device__ __forceinline__ float celu1(float x){
    return x > 0.0f ? x : (__expf(x) - 1.0f);
}
static __device__ __forceinline__ unsigned int pkh(float lo, float hi){
    f16x2 t = __builtin_amdgcn_cvt_pkrtz(lo, hi);
    return __builtin_bit_cast(unsigned int, t);
}

// ---------------- Kernel 0: seg boundaries + W3/W2 prep (merged) -------------
__global__ void setup_kernel(const int* __restrict__ out_index,
                             int* __restrict__ seg_start, int E, int N,
                             const float* __restrict__ W3, const float* __restrict__ W2,
                             __fp16* __restrict__ W3frag,
                             unsigned int* __restrict__ W2f16)
{
    int o = blockIdx.x * blockDim.x + threadIdx.x;
    if (o < E) {
        int cur = out_index[o];
        if (o == 0) {
            for (int v = 0; v <= cur; ++v) seg_start[v] = 0;
        } else {
            int prev = out_index[o - 1];
            for (int v = prev + 1; v <= cur; ++v) seg_start[v] = o;
        }
        if (o == E - 1) {
            for (int v = cur + 1; v <= N; ++v) seg_start[v] = E;
        }
    }
    if (o < 65536) {
        int j    = o & 7;
        int lane = (o >> 3) & 63;
        int t    = (o >> 9) & 3;
        int kk   = o >> 11;
        int k = kk * 32 + (lane >> 4) * 8 + j;
        int n = t * 16 + (lane & 15);
        W3frag[o] = (__fp16)W3[k * 64 + n];
    } else if (o < 65536 + 1024) {
        int o2 = o - 65536;
        int nt   = o2 >> 8;
        int lane = (o2 >> 2) & 63;
        int d    = o2 & 3;
        int q = lane >> 4, rr = lane & 15;
        unsigned int v = 0;
        if (q < 2) {
            int k0 = q * 8 + 2 * d;
            int n = nt * 16 + rr;
            v = pkh(W2[k0 * 64 + n], W2[(k0 + 1) * 64 + n]);
        }
        W2f16[o2] = v;
    }
}

// ---------------- Kernel 1: edge aggregation (pipelined all-MFMA) ------------
// Wave w owns points [4w, 4w+4). Batch = 64 slots (2x 32-slot K-steps).
// Pipeline: prefetch next batch's descriptors + in_index vector + pos rows
// while computing current batch. x-src indices via ds_bpermute of idx vector.
__global__ __launch_bounds__(256) void agg_kernel(
    const float* __restrict__ x_in, const float* __restrict__ pos_in,
    const float* __restrict__ pos_out, const int* __restrict__ in_index,
    const int* __restrict__ seg_start, const float* __restrict__ W1,
    const unsigned int* __restrict__ W2f16, __fp16* __restrict__ Pf16, int E)
{
    __shared__ __align__(16) unsigned char ldsraw[4 * 9216];
    int lane = threadIdx.x & 63;
    int wv = threadIdx.x >> 6;
    unsigned char* H2L = ldsraw + wv * 9216;   // staging 0..3071; tile rows m*144
    int w = blockIdx.x * 4 + wv;

    int r = lane & 15;
    int q = lane >> 4;
    int l31 = lane & 31;
    bool hihalf = lane >= 32;
    int vq = 32 * q;                           // byte-addr component for bpermute

    // zero block for padded-K A-frag lanes (bytes 9200..9215 never written)
    if (lane == 0) *(u32x4*)(H2L + 9200) = (u32x4){0u, 0u, 0u, 0u};

    // W2 B-frags (constant)
    f16x8 bfr[4];
    #pragma unroll
    for (int nt = 0; nt < 4; ++nt)
        bfr[nt] = __builtin_bit_cast(f16x8, *((const u32x4*)W2f16 + nt * 64 + lane));

    // W1 columns (uniform -> SGPRs)
    float w1a[16], w1b[16], w1c[16];
    #pragma unroll
    for (int c = 0; c < 16; ++c) { w1a[c] = W1[c]; w1b[c] = W1[16 + c]; w1c[c] = W1[32 + c]; }

    // per-wave point table (4 points, wave-uniform)
    int s5[5];
    #pragma unroll
    for (int i = 0; i < 5; ++i) s5[i] = rfl(seg_start[w * 4 + i]);
    int cf[4], cc[4], p[5];
    p[0] = 0;
    #pragma unroll
    for (int i = 0; i < 4; ++i) {
        cf[i] = s5[i + 1] - s5[i];
        cc[i] = cf[i] > 64 ? 64 : cf[i];
        p[i + 1] = p[i] + (cc[i] > 32 ? 2 : 1);
    }
    int ns = p[4];                             // total 32-slot steps, 4..8

    // descriptor for step t (wave-uniform; t >= ns yields rem<=0 -> all-pad)
    #define STEP_DESC(t, nS, cfS, remS, ebS)                         \
        {                                                            \
            int i_ = 0, pi_ = 0;                                     \
            _Pragma("unroll")                                        \
            for (int k_ = 1; k_ < 4; ++k_)                           \
                if ((t) >= p[k_]) { i_ = k_; pi_ = p[k_]; }          \
            int cf_ = cf[0], cc_ = cc[0], sg_ = s5[0];               \
            _Pragma("unroll")                                        \
            for (int k_ = 1; k_ < 4; ++k_)                           \
                if (i_ >= k_) { cf_ = cf[k_]; cc_ = cc[k_]; sg_ = s5[k_]; } \
            int kb_ = ((t) - pi_) * 32;                              \
            (nS) = w * 4 + i_; (cfS) = cf_;                          \
            (remS) = cc_ - kb_; (ebS) = sg_ + kb_;                   \
        }

    f32x4 C[4];
    #pragma unroll
    for (int mt = 0; mt < 4; ++mt) C[mt] = (f32x4){0.f, 0.f, 0.f, 0.f};
    int cur_n = w * 4;
    int cur_cf = cf[0];

    // ---- prologue: batch 0 descriptors + idx + pos prefetch ----
    int nA, cfA, remA, ebA, nB, cfB, remB, ebB;
    STEP_DESC(0, nA, cfA, remA, ebA)
    STEP_DESC(1, nB, cfB, remB, ebB)
    int nH = hihalf ? nB : nA;
    int ebH = hihalf ? ebB : ebA;
    int idx0 = ebH + l31; idx0 = idx0 < E ? idx0 : E - 1;
    int idxs = in_index[idx0];                 // lane l -> src of slot l
    float pox = pos_out[nH * 3 + 0];
    float poy = pos_out[nH * 3 + 1];
    float poz = pos_out[nH * 3 + 2];
    float pi0 = pos_in[idxs * 3 + 0];
    float pi1 = pos_in[idxs * 3 + 1];
    float pi2 = pos_in[idxs * 3 + 2];

    #pragma unroll 1
    for (int b = 0; b < 4; ++b) {
        if (2 * b >= ns) break;

        // ---- prefetch next batch: descriptors + idx vector ----
        int nA2, cfA2, remA2, ebA2, nB2, cfB2, remB2, ebB2;
        STEP_DESC(2 * b + 2, nA2, cfA2, remA2, ebA2)
        STEP_DESC(2 * b + 3, nB2, cfB2, remB2, ebB2)
        int nH2 = hihalf ? nB2 : nA2;
        int ebH2 = hihalf ? ebB2 : ebA2;
        int idx2 = ebH2 + l31; idx2 = idx2 < E ? idx2 : E - 1;
        int idxs_next = in_index[idx2];
        float pox2 = pos_out[nH2 * 3 + 0];
        float poy2 = pos_out[nH2 * 3 + 1];
        float poz2 = pos_out[nH2 * 3 + 2];

        // ---- x A-frags: src via bpermute of idxs, masked gather ----
        f16x8 ax[2];
        #pragma unroll
        for (int h = 0; h < 2; ++h) {
            int remS = h ? remB : remA;
            float xv[8];
            #pragma unroll
            for (int jj = 0; jj < 8; ++jj) {
                // slot = 32h + 8q + jj; bpermute byte addr = 4*slot
                int s = __builtin_amdgcn_ds_bpermute(128 * h + vq + 4 * jj, idxs);
                float x = x_in[s * 16 + r];
                xv[jj] = ((8 * q + jj) < remS) ? x : 0.0f;
            }
            u32x4 t;
            #pragma unroll
            for (int d = 0; d < 4; ++d) t[d] = pkh(xv[2 * d], xv[2 * d + 1]);
            ax[h] = __builtin_bit_cast(f16x8, t);
        }

        // ---- h1 (lane = slot): pos already prefetched ----
        float d0 = pi0 - pox;
        float d1 = pi1 - poy;
        float d2 = pi2 - poz;
        unsigned int hp[8];
        #pragma unroll
        for (int cp = 0; cp < 8; ++cp) {
            float a0 = celu1(fmaf(d0, w1a[2 * cp],     fmaf(d1, w1b[2 * cp],     d2 * w1c[2 * cp])));
            float a1 = celu1(fmaf(d0, w1a[2 * cp + 1], fmaf(d1, w1b[2 * cp + 1], d2 * w1c[2 * cp + 1])));
            hp[cp] = pkh(a0, a1);
        }
        *(u32x4*)(H2L + lane * 48)      = (u32x4){hp[0], hp[1], hp[2], hp[3]};
        *(u32x4*)(H2L + lane * 48 + 16) = (u32x4){hp[4], hp[5], hp[6], hp[7]};
        f16x8 af[4];
        #pragma unroll
        for (int et = 0; et < 4; ++et) {
            int abase = (q < 2) ? ((et * 16 + r) * 48 + q * 16) : 9200;
            af[et] = __builtin_bit_cast(f16x8, *(const u32x4*)(H2L + abase));
        }

        // ---- h2 = celu(h1 @ W2) via MFMA; tile write H2L[m][slot] ----
        #pragma unroll
        for (int pp = 0; pp < 2; ++pp) {
            f32x4 D[4][2];
            #pragma unroll
            for (int et = 0; et < 4; ++et)
                #pragma unroll
                for (int j = 0; j < 2; ++j)
                    D[et][j] = __builtin_amdgcn_mfma_f32_16x16x32_f16(
                        af[et], bfr[2 * pp + j], (f32x4){0.f, 0.f, 0.f, 0.f}, 0, 0, 0);
            #pragma unroll
            for (int et = 0; et < 4; ++et)
                #pragma unroll
                for (int j = 0; j < 2; ++j) {
                    int nt = 2 * pp + j;
                    float v0 = celu1(D[et][j][0]);
                    float v1 = celu1(D[et][j][1]);
                    float v2 = celu1(D[et][j][2]);
                    float v3 = celu1(D[et][j][3]);
                    *(u32x2*)(H2L + (nt * 16 + r) * 144 + et * 32 + q * 8) =
                        (u32x2){pkh(v0, v1), pkh(v2, v3)};
                }
        }

        // ---- pos prefetch for next batch (idxs_next has landed by now) ----
        float pi0n = pos_in[idxs_next * 3 + 0];
        float pi1n = pos_in[idxs_next * 3 + 1];
        float pi2n = pos_in[idxs_next * 3 + 2];

        // ---- P accumulation per half, flush on wave-uniform transitions ----
        #pragma unroll
        for (int h = 0; h < 2; ++h) {
            int nS  = h ? nB : nA;
            int cfS = h ? cfB : cfA;
            if (rfl(nS) != cur_n) {
                float inv = cur_cf > 0 ? 1.0f / (float)cur_cf : 0.0f;
                #pragma unroll
                for (int mt = 0; mt < 4; ++mt)
                    #pragma unroll
                    for (int i = 0; i < 4; ++i)
                        Pf16[(size_t)cur_n * 1024 + (q * 4 + i) * 64 + mt * 16 + r] =
                            (__fp16)(C[mt][i] * inv);
                #pragma unroll
                for (int mt = 0; mt < 4; ++mt) C[mt] = (f32x4){0.f, 0.f, 0.f, 0.f};
                cur_n = nS; cur_cf = cfS;
            }
            #pragma unroll
            for (int mt = 0; mt < 4; ++mt) {
                f16x8 bb = __builtin_bit_cast(f16x8,
                    *(u32x4*)(H2L + (mt * 16 + r) * 144 + h * 64 + q * 16));
                C[mt] = __builtin_amdgcn_mfma_f32_16x16x32_f16(ax[h], bb, C[mt], 0, 0, 0);
            }
        }

        // ---- rotate pipeline registers ----
        nA = nA2; cfA = cfA2; remA = remA2; ebA = ebA2;
        nB = nB2; cfB = cfB2; remB = remB2; ebB = ebB2;
        idxs = idxs_next;
        pox = pox2; poy = poy2; poz = poz2;
        pi0 = pi0n; pi1 = pi1n; pi2 = pi2n;
    }

    // final flush
    {
        float inv = cur_cf > 0 ? 1.0f / (float)cur_cf : 0.0f;
        #pragma unroll
        for (int mt = 0; mt < 4; ++mt)
            #pragma unroll
            for (int i = 0; i < 4; ++i)
                Pf16[(size_t)cur_n * 1024 + (q * 4 + i) * 64 + mt * 16 + r] =
                    (__fp16)(C[mt][i] * inv);
    }
    #undef STEP_DESC
}

// ---------------- Kernel 2: out = Pf16 @ W3 + b3 (f16 MFMA) ------------------
__global__ __launch_bounds__(256) void gemm_kernel(
    const __fp16* __restrict__ Pf16,
    const __fp16* __restrict__ W3frag,
    const float* __restrict__ b3, float* __restrict__ out)
{
    int lane = threadIdx.x & 63;
    int w = blockIdx.x * 4 + (threadIdx.x >> 6);
    int ptile = w >> 2;
    int ntile = w & 3;
    int quad = lane >> 4;
    int r = lane & 15;

    const short8* Arow = (const short8*)(Pf16 + (size_t)(ptile * 16 + r) * 1024 + quad * 8);
    const short8* Bp   = (const short8*)W3frag + (size_t)ntile * 64 + lane;

    f32x4 acc = {0.0f, 0.0f, 0.0f, 0.0f};
    #pragma unroll 8
    for (int kk = 0; kk < 32; ++kk) {
        f16x8 a = __builtin_bit_cast(f16x8, Arow[kk * 4]);
        f16x8 b = __builtin_bit_cast(f16x8, Bp[(size_t)kk * 256]);
        acc = __builtin_amdgcn_mfma_f32_16x16x32_f16(a, b, acc, 0, 0, 0);
    }

    int outcol = ntile * 16 + r;
    float bias = b3[outcol];
    #pragma unroll
    for (int i = 0; i < 4; ++i) {
        int prow = ptile * 16 + quad * 4 + i;
        out[(size_t)prow * 64 + outcol] = acc[i] + bias;
    }
}

extern "C" void kernel_launch(void* const* d_in, const int* in_sizes, int n_in,
                              void* d_out, int out_size, void* d_ws, size_t ws_size,
                              hipStream_t stream)
{
    const float* x_in    = (const float*)d_in[0];
    const float* pos_in  = (const float*)d_in[1];
    const float* pos_out = (const float*)d_in[2];
    const int* in_index  = (const int*)d_in[3];
    const int* out_index = (const int*)d_in[4];
    const float* W1 = (const float*)d_in[5];
    const float* W2 = (const float*)d_in[6];
    const float* W3 = (const float*)d_in[7];
    const float* b3 = (const float*)d_in[8];

    int N = in_sizes[0] / 16;    // 32768
    int E = in_sizes[3];         // 786432
    float* out = (float*)d_out;

    // workspace: Pf16 (64MB) | seg (N+1) | W3frag (128KB) | W2f16 (4KB)
    char* ws = (char*)d_ws;
    __fp16* Pf16 = (__fp16*)ws;
    size_t off = (size_t)N * 1024 * 2;
    int* seg = (int*)(ws + off);
    off += (((size_t)(N + 1) * 4 + 255) & ~(size_t)255);
    __fp16* W3frag = (__fp16*)(ws + off);
    off += (size_t)65536 * 2;
    unsigned int* W2f16 = (unsigned int*)(ws + off);

    setup_kernel<<<(E + 255) / 256, 256, 0, stream>>>(out_index, seg, E, N,
                                                      W3, W2, W3frag, W2f16);
    agg_kernel<<<N / 16, 256, 0, stream>>>(x_in, pos_in, pos_out, in_index, seg,
                                           W1, W2f16, Pf16, E);
    gemm_kernel<<<N / 16, 256, 0, stream>>>(Pf16, W3frag, b3, out);
}